// Round 1
// baseline (86.396 us; speedup 1.0000x reference)
//
#include <hip/hip_runtime.h>
#include <math.h>

// Steerable CNP target prediction on MI355X.
//
// Math: output[t,c] = sum_{i,j} Kx[t,i]*Ky[t,j]*FM[c,j,i] / (Sx[t]*Sy[t])
//  with Kx[t,i] = exp(-(xt0-ax[i])^2 / (2 l^2)), Sx = sum_i Kx,
//  FM channels 2,3 passed through softplus first.
// The RBF kernel on the regular tensor-product grid factorizes exactly,
// so we never materialize the [8192 x 16384] kernel matrix.

#define NA      128   // grid axis size
#define TT      16    // targets per block
#define THREADS 512   // 4 channels x 128 i-columns

__global__ __launch_bounds__(THREADS)
void cnp_factorized_kernel(const float* __restrict__ fm,    // [4][NA][NA] (c,y,x)
                           const float* __restrict__ grid,  // [NA*NA][2]
                           const float* __restrict__ xt,    // [T][2]
                           const float* __restrict__ lsp,   // [1]
                           float* __restrict__ out,         // [2*T*2] means then sigmas
                           int n_target)
{
    __shared__ __attribute__((aligned(16))) float Kx[TT * NA];
    __shared__ __attribute__((aligned(16))) float Ky[TT * NA];
    __shared__ float red[4][2][TT];   // numer partials per (c, wave-half, t)
    __shared__ float sred[2][2][TT];  // Sx / Sy partials per (axis, wave-half, t)

    const int tid = threadIdx.x;
    const int c   = tid >> 7;     // channel 0..3 (wave-uniform: 2 waves per channel)
    const int i   = tid & 127;    // i-column 0..127
    const int t0  = blockIdx.x * TT;

    const float l      = lsp[0];
    const float inv2l2 = 0.5f / (l * l);

    // ---- phase 0: per-target separable kernel rows into LDS ----
    // grid[j] = (ax[0], ax[j])  =>  ax[j] = grid[j*2+1]
    for (int k = tid; k < TT * NA; k += THREADS) {
        const int t = k >> 7;
        const int j = k & 127;
        const int tg = t0 + t;
        const float ax = grid[j * 2 + 1];
        const float x0 = xt[tg * 2 + 0];
        const float x1 = xt[tg * 2 + 1];
        const float dx = x0 - ax;
        const float dy = x1 - ax;
        Kx[k] = __expf(-dx * dx * inv2l2);
        Ky[k] = __expf(-dy * dy * inv2l2);
    }
    __syncthreads();

    // ---- phase 1: V[t] = sum_j Ky[t,j] * FM[c,j,i] ----
    float V[TT];
#pragma unroll
    for (int t = 0; t < TT; ++t) V[t] = 0.0f;

    const float* base = fm + c * (NA * NA) + i;   // walk down column i of channel c
    for (int j = 0; j < NA; j += 4) {
        float f0 = base[(j + 0) * NA];
        float f1 = base[(j + 1) * NA];
        float f2 = base[(j + 2) * NA];
        float f3 = base[(j + 3) * NA];
        if (c >= 2) {   // softplus, wave-uniform branch
            f0 = (f0 > 15.0f) ? f0 : log1pf(__expf(f0));
            f1 = (f1 > 15.0f) ? f1 : log1pf(__expf(f1));
            f2 = (f2 > 15.0f) ? f2 : log1pf(__expf(f2));
            f3 = (f3 > 15.0f) ? f3 : log1pf(__expf(f3));
        }
#pragma unroll
        for (int t = 0; t < TT; ++t) {
            const float4 k4 = *reinterpret_cast<const float4*>(&Ky[t * NA + j]);
            V[t] = fmaf(k4.x, f0,
                    fmaf(k4.y, f1,
                     fmaf(k4.z, f2,
                      fmaf(k4.w, f3, V[t]))));
        }
    }

    // ---- phase 2: numer[t,c] = sum_i Kx[t,i]*V[t]; Sx, Sy reductions ----
    const int half = (tid >> 6) & 1;   // which i-half this wave covers
    const int lane = tid & 63;

#pragma unroll
    for (int t = 0; t < TT; ++t) {
        float v = Kx[t * NA + i] * V[t];
#pragma unroll
        for (int s = 32; s > 0; s >>= 1) v += __shfl_xor(v, s);
        if (lane == 0) red[c][half][t] = v;
    }
    if (c == 0) {                       // Sx on channel-0 waves
#pragma unroll
        for (int t = 0; t < TT; ++t) {
            float v = Kx[t * NA + i];
#pragma unroll
            for (int s = 32; s > 0; s >>= 1) v += __shfl_xor(v, s);
            if (lane == 0) sred[0][half][t] = v;
        }
    } else if (c == 1) {                // Sy on channel-1 waves
#pragma unroll
        for (int t = 0; t < TT; ++t) {
            float v = Ky[t * NA + i];
#pragma unroll
            for (int s = 32; s > 0; s >>= 1) v += __shfl_xor(v, s);
            if (lane == 0) sred[1][half][t] = v;
        }
    }
    __syncthreads();

    // ---- phase 3: combine halves, normalize, write ----
    if (tid < 4 * TT) {
        const int t  = tid & (TT - 1);
        const int cc = tid >> 4;        // requires TT == 16
        const int tg = t0 + t;
        if (tg < n_target) {
            const float numer = red[cc][0][t] + red[cc][1][t];
            const float Sx = sred[0][0][t] + sred[0][1][t];
            const float Sy = sred[1][0][t] + sred[1][1][t];
            const float val = numer / (Sx * Sy);
            if (cc < 2) out[tg * 2 + cc] = val;                       // means
            else        out[n_target * 2 + tg * 2 + (cc - 2)] = val; // sigmas
        }
    }
}

extern "C" void kernel_launch(void* const* d_in, const int* in_sizes, int n_in,
                              void* d_out, int out_size, void* d_ws, size_t ws_size,
                              hipStream_t stream) {
    const float* fm   = (const float*)d_in[0];  // feature_map [4,128,128]
    const float* grid = (const float*)d_in[1];  // grid [16384,2]
    const float* xt   = (const float*)d_in[2];  // X_target [T,2]
    const float* lsp  = (const float*)d_in[3];  // l_scale [1]
    float* out = (float*)d_out;

    const int n_target = in_sizes[2] / 2;       // 8192
    const int blocks = (n_target + TT - 1) / TT;

    hipLaunchKernelGGL(cnp_factorized_kernel, dim3(blocks), dim3(THREADS), 0, stream,
                       fm, grid, xt, lsp, out, n_target);
}

// Round 2
// 28.861 us; speedup vs baseline: 2.9935x; 2.9935x over previous
//
#include <hip/hip_runtime.h>
#include <math.h>

// Steerable CNP target prediction — separable-RBF factorization.
//
// out[t,c] = (sum_i Kx[t,i] * sum_j Ky[t,j] * FMc[j,i]) / (Sx[t]*Sy[t])
// Kx[t,i] = exp(-(xt0 - ax[i])^2 / (2 l^2)), channels 2,3 softplus'd first.
//
// Round-2 fixes vs round 1 (which scratch-thrashed: VGPR=24, FETCH=1.16GB):
//  - accumulators are NAMED float4s (compile-time static indexing only)
//  - 4 i-columns per thread => 16 FMA per ds_read_b128 of Ky
//  - softplus precomputed once into d_ws by a tiny pre-kernel

#define NA      128
#define TT      8     // targets per block -> 1024 blocks
#define THREADS 256   // 4 waves; wave == channel; lane: jh=lane>>5, ig=lane&31

// ---------- pre-kernel: softplus(FM[2:4]) -> sp (2*128*128 floats) ----------
__global__ __launch_bounds__(256)
void softplus_pre(const float* __restrict__ fm, float* __restrict__ sp)
{
    const int idx = blockIdx.x * 256 + threadIdx.x;          // float4 index
    const int n4  = 2 * NA * NA / 4;                         // 8192
    if (idx >= n4) return;
    float4 v = reinterpret_cast<const float4*>(fm + 2 * NA * NA)[idx];
    v.x = (v.x > 15.0f) ? v.x : log1pf(__expf(v.x));
    v.y = (v.y > 15.0f) ? v.y : log1pf(__expf(v.y));
    v.z = (v.z > 15.0f) ? v.z : log1pf(__expf(v.z));
    v.w = (v.w > 15.0f) ? v.w : log1pf(__expf(v.w));
    reinterpret_cast<float4*>(sp)[idx] = v;
}

// ---------- main kernel ----------
__global__ __launch_bounds__(THREADS)
void cnp_main(const float* __restrict__ fm,    // [4][NA][NA]
              const float* __restrict__ sp,    // [2][NA][NA] softplus'd c2,c3
              const float* __restrict__ grid,  // [NA*NA][2]
              const float* __restrict__ xt,    // [T][2]
              const float* __restrict__ lsp,   // [1]
              float* __restrict__ out,         // means [T][2] then sigmas [T][2]
              int n_target, int use_sp)
{
    __shared__ __attribute__((aligned(16))) float Kx[TT * NA];
    __shared__ __attribute__((aligned(16))) float Ky[TT * NA];
    __shared__ float red[4][TT];
    __shared__ float sxy[2][TT];

    const int tid  = threadIdx.x;
    const int c    = tid >> 6;        // wave index == channel
    const int lane = tid & 63;
    const int jh   = lane >> 5;       // which j-half this lane sums
    const int ig   = lane & 31;       // i-group
    const int i4   = ig * 4;          // first of this thread's 4 i-columns
    const int t0   = blockIdx.x * TT;

    const float l      = lsp[0];
    const float inv2l2 = 0.5f / (l * l);

    // ---- phase 0: separable kernel rows into LDS ----
    // grid[g] = (ax[g>>7], ax[g&127])  =>  ax[j] = grid[j*2+1]
    for (int k = tid; k < TT * NA; k += THREADS) {
        const int t = k >> 7;
        const int j = k & 127;
        const int tg = t0 + t;
        const float ax = grid[j * 2 + 1];
        const float x0 = xt[tg * 2 + 0];
        const float x1 = xt[tg * 2 + 1];
        const float dx = x0 - ax;
        const float dy = x1 - ax;
        Kx[k] = __expf(-dx * dx * inv2l2);
        Ky[k] = __expf(-dy * dy * inv2l2);
    }
    __syncthreads();

    // ---- phase 1: per-thread V[t][4i] = sum_{j in my half} Ky[t,j]*FMc[j,i] ----
    const float* src = (c < 2 || !use_sp) ? (fm + c * NA * NA)
                                          : (sp + (c - 2) * NA * NA);
    const bool do_sp_inline = (!use_sp) && (c >= 2);

    float4 v0, v1, v2, v3, v4, v5, v6, v7;
    v0 = v1 = v2 = v3 = v4 = v5 = v6 = v7 = make_float4(0.f, 0.f, 0.f, 0.f);

    const int jb0 = jh * 64;
    for (int g = 0; g < 16; ++g) {
        const int j = jb0 + g * 4;
        float4 f0 = *reinterpret_cast<const float4*>(&src[(j + 0) * NA + i4]);
        float4 f1 = *reinterpret_cast<const float4*>(&src[(j + 1) * NA + i4]);
        float4 f2 = *reinterpret_cast<const float4*>(&src[(j + 2) * NA + i4]);
        float4 f3 = *reinterpret_cast<const float4*>(&src[(j + 3) * NA + i4]);
        if (do_sp_inline) {   // fallback only if ws too small
#define SP1(z) z = (z > 15.0f) ? z : log1pf(__expf(z))
            SP1(f0.x); SP1(f0.y); SP1(f0.z); SP1(f0.w);
            SP1(f1.x); SP1(f1.y); SP1(f1.z); SP1(f1.w);
            SP1(f2.x); SP1(f2.y); SP1(f2.z); SP1(f2.w);
            SP1(f3.x); SP1(f3.y); SP1(f3.z); SP1(f3.w);
#undef SP1
        }
#define STEP(T, V)                                                             \
        {                                                                      \
            const float4 k4 = *reinterpret_cast<const float4*>(&Ky[(T) * NA + j]); \
            V.x = fmaf(k4.x, f0.x, fmaf(k4.y, f1.x, fmaf(k4.z, f2.x, fmaf(k4.w, f3.x, V.x)))); \
            V.y = fmaf(k4.x, f0.y, fmaf(k4.y, f1.y, fmaf(k4.z, f2.y, fmaf(k4.w, f3.y, V.y)))); \
            V.z = fmaf(k4.x, f0.z, fmaf(k4.y, f1.z, fmaf(k4.z, f2.z, fmaf(k4.w, f3.z, V.z)))); \
            V.w = fmaf(k4.x, f0.w, fmaf(k4.y, f1.w, fmaf(k4.z, f2.w, fmaf(k4.w, f3.w, V.w)))); \
        }
        STEP(0, v0) STEP(1, v1) STEP(2, v2) STEP(3, v3)
        STEP(4, v4) STEP(5, v5) STEP(6, v6) STEP(7, v7)
#undef STEP
    }

    // ---- phase 2: numer[t,c] = 64-lane reduce of Kx[t,i]*V ----
#define RED(T, V)                                                              \
    {                                                                          \
        const float4 kx4 = *reinterpret_cast<const float4*>(&Kx[(T) * NA + i4]); \
        float w = fmaf(kx4.x, V.x, fmaf(kx4.y, V.y, fmaf(kx4.z, V.z, kx4.w * V.w))); \
        w += __shfl_xor(w, 1);  w += __shfl_xor(w, 2);  w += __shfl_xor(w, 4); \
        w += __shfl_xor(w, 8);  w += __shfl_xor(w, 16); w += __shfl_xor(w, 32); \
        if (lane == 0) red[c][(T)] = w;                                        \
    }
    RED(0, v0) RED(1, v1) RED(2, v2) RED(3, v3)
    RED(4, v4) RED(5, v5) RED(6, v6) RED(7, v7)
#undef RED

    // Sx (jh=0 lanes) / Sy (jh=1 lanes) on the c==0 wave; 32-wide reduce
    if (c == 0) {
        const float* kb = jh ? Ky : Kx;
#define SRED(T)                                                                \
        {                                                                      \
            const float4 q = *reinterpret_cast<const float4*>(&kb[(T) * NA + i4]); \
            float u = (q.x + q.y) + (q.z + q.w);                               \
            u += __shfl_xor(u, 1); u += __shfl_xor(u, 2); u += __shfl_xor(u, 4); \
            u += __shfl_xor(u, 8); u += __shfl_xor(u, 16);                     \
            if (ig == 0) sxy[jh][(T)] = u;                                     \
        }
        SRED(0) SRED(1) SRED(2) SRED(3) SRED(4) SRED(5) SRED(6) SRED(7)
#undef SRED
    }
    __syncthreads();

    // ---- phase 3: normalize + write (32 outputs per block) ----
    if (tid < 4 * TT) {
        const int t  = tid & (TT - 1);
        const int cc = tid >> 3;            // requires TT == 8
        const int tg = t0 + t;
        if (tg < n_target) {
            const float val = red[cc][t] / (sxy[0][t] * sxy[1][t]);
            if (cc < 2) out[tg * 2 + cc] = val;                        // means
            else        out[n_target * 2 + tg * 2 + (cc - 2)] = val;   // sigmas
        }
    }
}

extern "C" void kernel_launch(void* const* d_in, const int* in_sizes, int n_in,
                              void* d_out, int out_size, void* d_ws, size_t ws_size,
                              hipStream_t stream) {
    const float* fm   = (const float*)d_in[0];
    const float* grid = (const float*)d_in[1];
    const float* xt   = (const float*)d_in[2];
    const float* lsp  = (const float*)d_in[3];
    float* out = (float*)d_out;
    float* sp  = (float*)d_ws;

    const int n_target = in_sizes[2] / 2;                 // 8192
    const size_t sp_bytes = (size_t)2 * NA * NA * sizeof(float);
    const int use_sp = (ws_size >= sp_bytes) ? 1 : 0;

    if (use_sp) {
        const int n4 = 2 * NA * NA / 4;                   // 8192 float4s
        hipLaunchKernelGGL(softplus_pre, dim3((n4 + 255) / 256), dim3(256), 0, stream,
                           fm, sp);
    }
    const int blocks = (n_target + TT - 1) / TT;          // 1024
    hipLaunchKernelGGL(cnp_main, dim3(blocks), dim3(THREADS), 0, stream,
                       fm, sp, grid, xt, lsp, out, n_target, use_sp);
}